// Round 3
// baseline (679.177 us; speedup 1.0000x reference)
//
#include <hip/hip_runtime.h>
#include <hip/hip_bf16.h>

// ============================================================================
// UpConvsample2d via bf16 MFMA.
//
// Math (verified in round 1):
//   W1[c,o,a,b] = w[((c*256+o)*3+a)*3+b]
//   y1 parity planes p=(h'&1)*2+(w'&1), each 64x64 per (n,o):
//     ph=0 row taps: (r=i-1,a=2),(r=i,a=0)   ph=1: (r=i,a=1)   (cols same)
//   out = 3x3 FIR {0.4,1.2,0.4}^2 over y1 with top/left pad 2, crop 128x128.
//
// Phases:
//   1. prep: w -> wp[ab][o][c] bf16 + zero-pad row/col 0 of xp   (merged, r3)
//      pack_x: x -> xp[n][65][65][512] bf16, float4 global reads (r3)
//   2. mfma_conv: per parity, sum over taps of GEMM (M=spatial, N=o, K=c)
//      128x128 tile, 4 waves x (64x64), 16x16x32 bf16 MFMA, global_load_lds(16B)
//      XCD-chunk swizzle (r3): XCD x owns m-tiles [64x,64x+64), parity fastest,
//      so the 8 blocks sharing one m-tile's A-rows co-reside on one XCD/L2.
//   3. fir_kernel: per (n,o) plane, stage 4 parity planes in LDS (short8
//      coalesced), quad-pair per thread via 4B word reads, float4 stores.
// ============================================================================

typedef __attribute__((ext_vector_type(8))) short short8;
typedef __attribute__((ext_vector_type(4))) float float4v;

#define XP_ELEMS ((size_t)16 * 65 * 65 * 512)   // 34,611,200
#define WP_ELEMS ((size_t)9 * 256 * 512)        // 1,179,648
#define YP_ELEMS ((size_t)4 * 16 * 256 * 4096)  // 67,108,864

__device__ __forceinline__ void gl_lds16(const __hip_bfloat16* g, __hip_bfloat16* l) {
    __builtin_amdgcn_global_load_lds(
        (const __attribute__((address_space(1))) void*)g,
        (__attribute__((address_space(3))) void*)l, 16, 0, 0);
}

// --------------------------------------------------------------- prep -------
// idx < WP_ELEMS: pack w.  idx < 16*65*512: zero-pad xp row 0 / col 0.
__global__ __launch_bounds__(256) void prep_kernel(
    const float* __restrict__ w, __hip_bfloat16* __restrict__ wp,
    __hip_bfloat16* __restrict__ xp) {
    int idx = blockIdx.x * 256 + (int)threadIdx.x;  // 0 .. 9*256*512
    {   // ---- pack_w ----
        int c  = idx & 511;
        int o  = (idx >> 9) & 255;
        int ab = idx >> 17;                  // 0..8
        int a = ab / 3, b = ab % 3;
        wp[idx] = __float2bfloat16(w[((size_t)(c * 256 + o) * 3 + a) * 3 + b]);
    }
    if (idx < 16 * 65 * 512) {  // ---- zero-pad ----
        int c = idx & 511;
        int t = (idx >> 9) % 65;
        int n = idx / (65 * 512);
        __hip_bfloat16 z = __float2bfloat16(0.f);
        xp[(((size_t)(n * 65) + 0) * 65 + t) * 512 + c] = z;   // pad row 0
        xp[(((size_t)(n * 65) + t) * 65 + 0) * 512 + c] = z;   // pad col 0
    }
}

__global__ __launch_bounds__(256) void pack_x_kernel(
    const float* __restrict__ x, __hip_bfloat16* __restrict__ xp) {
    int i = blockIdx.x;       // 0..63
    int n = blockIdx.y;       // 0..15
    int tid = (int)threadIdx.x;
    __shared__ float tile[64][65];
    const int j4 = (tid & 15) * 4;
    for (int c0 = 0; c0 < 512; c0 += 64) {
        __syncthreads();
        // read: float4 per lane, 1KB per wave instr; 4 iters cover 64 ch x 64 j
#pragma unroll
        for (int rr = 0; rr < 4; rr++) {
            int cl = rr * 16 + (tid >> 4);
            float4v v = *(const float4v*)(
                x + (((size_t)(n * 512 + c0 + cl) * 64) + i) * 64 + j4);
#pragma unroll
            for (int t = 0; t < 4; t++) tile[cl][j4 + t] = v[t];
        }
        __syncthreads();
        // write: 512 tasks = 64 j x 8 channel-groups of 8; ushort8 stores
#pragma unroll
        for (int pass = 0; pass < 2; pass++) {
            int task = pass * 256 + tid;
            int j  = task >> 3;          // 0..63
            int cg = task & 7;           // channel group of 8
            union { short8 v; unsigned short h[8]; } u;
#pragma unroll
            for (int r = 0; r < 8; r++) {
                __hip_bfloat16 b = __float2bfloat16(tile[cg * 8 + r][j]);
                u.h[r] = *(unsigned short*)&b;
            }
            *(short8*)(xp + (((size_t)(n * 65) + i + 1) * 65 + (j + 1)) * 512 +
                       c0 + cg * 8) = u.v;
        }
    }
}

// ---------------------------------------------------------------- mfma conv -
// grid: 4096 blocks 1-D, block 256 (4 waves).
// XCD swizzle: xcd=flat&7 owns pos=flat>>3; nf=xcd*512+pos; decode parity
// fastest so per-XCD work is parity-balanced and same-mt blocks co-reside.
__global__ __launch_bounds__(256) void mfma_conv_kernel(
    const __hip_bfloat16* __restrict__ xp, const __hip_bfloat16* __restrict__ wp,
    __hip_bfloat16* __restrict__ yp) {
    const int flat = (int)blockIdx.x;
    const int nf   = ((flat & 7) << 9) + (flat >> 3);   // bijective, 4096%8==0
    const int p    = nf & 3;                            // parity (balanced/XCD)
    const int o0   = ((nf >> 2) & 1) * 128;
    const int mt   = nf >> 3;                           // 0..511
    const int ph = p >> 1, pw = p & 1;
    const int n  = mt >> 5;
    const int i0 = (mt & 31) << 1;      // block covers rows i0, i0+1
    const int tid  = (int)threadIdx.x;
    const int wave = tid >> 6, lane = tid & 63;
    const int wm = wave & 1, wn = wave >> 1;
    const int lrow = lane & 15, quad = lane >> 4;
    const int m0j   = wave * 16 + (lane >> 2);   // A/B tile row this lane stages
    const int klane = (lane & 3) * 8;            // k element offset this lane stages

    __shared__ __align__(16) __hip_bfloat16 lA[128 * 32];
    __shared__ __align__(16) __hip_bfloat16 lB[128 * 32];

    float4v acc[4][4];
#pragma unroll
    for (int fm = 0; fm < 4; fm++)
#pragma unroll
        for (int fn = 0; fn < 4; fn++) acc[fm][fn] = (float4v)0.f;

    __hip_bfloat16* la0 = lA + wave * 512;          // e=0 rows (di=0)
    __hip_bfloat16* la1 = lA + 2048 + wave * 512;   // e=1 rows (di=1)
    __hip_bfloat16* lb0 = lB + wave * 512;
    __hip_bfloat16* lb1 = lB + 2048 + wave * 512;

    const int nrt = ph ? 1 : 2, nct = pw ? 1 : 2;
    for (int rt = 0; rt < nrt; rt++) {
        const int drp = ph ? 1 : rt;            // padded row offset: r+1 = i + drp
        const int a   = ph ? 1 : (rt ? 0 : 2);
        for (int ct = 0; ct < nct; ct++) {
            const int dsp = pw ? 1 : ct;
            const int b   = pw ? 1 : (ct ? 0 : 2);
            const int ab  = a * 3 + b;
            const __hip_bfloat16* A0 =
                xp + (((size_t)(n * 65 + i0 + drp)) * 65 + m0j + dsp) * 512 + klane;
            const __hip_bfloat16* A1 = A0 + (size_t)65 * 512;
            const __hip_bfloat16* B0 =
                wp + ((size_t)(ab * 256 + o0 + m0j)) * 512 + klane;
            const __hip_bfloat16* B1 = B0 + (size_t)64 * 512;

            for (int c0 = 0; c0 < 512; c0 += 32) {
                __syncthreads();
                gl_lds16(A0 + c0, la0);
                gl_lds16(A1 + c0, la1);
                gl_lds16(B0 + c0, lb0);
                gl_lds16(B1 + c0, lb1);
                __syncthreads();
                short8 af[4], bv[4];
#pragma unroll
                for (int fm = 0; fm < 4; fm++)
                    af[fm] = *(const short8*)(lA + ((wm * 64 + fm * 16 + lrow) * 32 + quad * 8));
#pragma unroll
                for (int fn = 0; fn < 4; fn++)
                    bv[fn] = *(const short8*)(lB + ((wn * 64 + fn * 16 + lrow) * 32 + quad * 8));
#pragma unroll
                for (int fm = 0; fm < 4; fm++)
#pragma unroll
                    for (int fn = 0; fn < 4; fn++)
                        acc[fm][fn] = __builtin_amdgcn_mfma_f32_16x16x32_bf16(
                            af[fm], bv[fn], acc[fm][fn], 0, 0, 0);
            }
        }
    }

    // epilogue: D row=(quad*4+reg) -> j, col=lrow -> o ; 4 consecutive j per lane
#pragma unroll
    for (int fm = 0; fm < 4; fm++) {
        int j0 = fm * 16 + quad * 4;
#pragma unroll
        for (int fn = 0; fn < 4; fn++) {
            int o = o0 + wn * 64 + fn * 16 + lrow;
            union { ushort4 v; __hip_bfloat16 h[4]; } u;
#pragma unroll
            for (int r = 0; r < 4; r++) u.h[r] = __float2bfloat16(acc[fm][fn][r]);
            *(ushort4*)(yp + (((size_t)(p * 4096 + n * 256 + o)) << 12) +
                        ((i0 + wm) << 6) + j0) = u.v;
        }
    }
}

// ---------------------------------------------------------------- FIR -------
// one block per (n,o) plane. Stage 4 parity planes (32KB) in LDS via short8,
// each thread computes a quad-pair (2 out rows x 4 out cols) per iteration.
__device__ __forceinline__ float bf_lo(unsigned u) { return __uint_as_float(u << 16); }
__device__ __forceinline__ float bf_hi(unsigned u) { return __uint_as_float(u & 0xffff0000u); }

__global__ __launch_bounds__(256) void fir_kernel(
    const __hip_bfloat16* __restrict__ yp, float* __restrict__ out) {
    const int no  = blockIdx.x;          // n*256 + o
    const int tid = (int)threadIdx.x;

    __shared__ __align__(16) unsigned short ylds[4 * 64 * 64];  // [q][ih][jw], 32KB

    // stage: 4 planes x 4096 bf16 = 2048 short8 chunks, fully coalesced
    const unsigned short* ysrc = (const unsigned short*)yp;
#pragma unroll
    for (int k = 0; k < 8; k++) {
        int chunk = k * 256 + tid;           // 0..2047
        int q   = chunk >> 9;                // 0..3
        int off = (chunk & 511) << 3;        // element offset in plane
        *(short8*)(ylds + q * 4096 + off) =
            *(const short8*)(ysrc + (((size_t)(q * 4096 + no)) << 12) + off);
    }
    __syncthreads();

    const unsigned* yw = (const unsigned*)ylds;  // word view: [q][ih][w], w=0..31

    const int qp = tid & 31;     // quad-pair: covers out cols 4qp..4qp+3
    const int iw = tid >> 5;     // 0..7

    // weight of plane-parity q, offset k, for output sub-parity e
    const float rw[2][2][2] = {{{0.4f, 0.4f}, {1.2f, 0.f}},
                               {{0.f, 1.2f}, {0.4f, 0.4f}}};  // [e][q][k]

    for (int s = 0; s < 8; s++) {
        const int I = s * 8 + iw;            // 0..63 (out rows 2I, 2I+1)

        // Y3[ph][pw][k][m]: cols {2qp-1, 2qp, 2qp+1} of plane (ph,pw), row I-1+k
        float Y3[2][2][2][3];
#pragma unroll
        for (int q = 0; q < 4; q++) {
            int phh = q >> 1, pww = q & 1;
#pragma unroll
            for (int k = 0; k < 2; k++) {
                int ih = I - 1 + k;
                float c0 = 0.f, c1 = 0.f, c2 = 0.f;
                if (ih >= 0) {
                    const unsigned* row = yw + (q * 64 + ih) * 32;
                    unsigned wb = row[qp];
                    c1 = bf_lo(wb);
                    c2 = bf_hi(wb);
                    if (qp > 0) c0 = bf_hi(row[qp - 1]);
                }
                Y3[phh][pww][k][0] = c0;
                Y3[phh][pww][k][1] = c1;
                Y3[phh][pww][k][2] = c2;
            }
        }

        float res[2][4];
#pragma unroll
        for (int t = 0; t < 2; t++) {        // quad t: J = 2qp+t, taps cols {t, t+1}
            float cs[2][2][2];               // [ph][k][ew]
#pragma unroll
            for (int phh = 0; phh < 2; phh++)
#pragma unroll
                for (int k = 0; k < 2; k++)
#pragma unroll
                    for (int ew = 0; ew < 2; ew++) {
                        float sv = 0.f;
#pragma unroll
                        for (int pww = 0; pww < 2; pww++)
#pragma unroll
                            for (int l = 0; l < 2; l++)
                                sv += rw[ew][pww][l] * Y3[phh][pww][k][t + l];
                        cs[phh][k][ew] = sv;
                    }
#pragma unroll
            for (int eh = 0; eh < 2; eh++)
#pragma unroll
                for (int ew = 0; ew < 2; ew++) {
                    float sv = 0.f;
#pragma unroll
                    for (int phh = 0; phh < 2; phh++)
#pragma unroll
                        for (int k = 0; k < 2; k++)
                            sv += rw[eh][phh][k] * cs[phh][k][ew];
                    res[eh][t * 2 + ew] = sv;
                }
        }

        size_t base = ((size_t)no << 14) + ((size_t)(2 * I) << 7) + 4 * qp;
        float4v v0 = {res[0][0], res[0][1], res[0][2], res[0][3]};
        float4v v1 = {res[1][0], res[1][1], res[1][2], res[1][3]};
        *(float4v*)(out + base)       = v0;
        *(float4v*)(out + base + 128) = v1;
    }
}

// ------------------------------------------------- fallback (ws too small) --
__global__ __launch_bounds__(256) void fused_direct_kernel(
    const float* __restrict__ x, const float* __restrict__ w,
    float* __restrict__ out) {
    int idx = blockIdx.x * 256 + (int)threadIdx.x;
    int w_ = idx & 127, h = (idx >> 7) & 127, no = idx >> 14;
    int o = no & 255, n = no >> 8;
    int I = h >> 1, J = w_ >> 1;
    const float fr0 = 0.4f, fr1 = 1.2f, fr2 = 0.4f;
    float gh[3][3]; int rh[3]; int nh;
    if ((h & 1) == 0) {
        nh = 3;
        rh[0] = I - 2; gh[0][0] = 0.f; gh[0][1] = 0.f; gh[0][2] = fr0;
        rh[1] = I - 1; gh[1][0] = fr0; gh[1][1] = fr1; gh[1][2] = fr2;
        rh[2] = I;     gh[2][0] = fr2; gh[2][1] = 0.f; gh[2][2] = 0.f;
    } else {
        nh = 2;
        rh[0] = I - 1; gh[0][0] = 0.f; gh[0][1] = fr0; gh[0][2] = fr1;
        rh[1] = I;     gh[1][0] = fr1; gh[1][1] = fr2; gh[1][2] = 0.f;
    }
    float gw[3][3]; int cw[3]; int nw;
    if ((w_ & 1) == 0) {
        nw = 3;
        cw[0] = J - 2; gw[0][0] = 0.f; gw[0][1] = 0.f; gw[0][2] = fr0;
        cw[1] = J - 1; gw[1][0] = fr0; gw[1][1] = fr1; gw[1][2] = fr2;
        cw[2] = J;     gw[2][0] = fr2; gw[2][1] = 0.f; gw[2][2] = 0.f;
    } else {
        nw = 2;
        cw[0] = J - 1; gw[0][0] = 0.f; gw[0][1] = fr0; gw[0][2] = fr1;
        cw[1] = J;     gw[1][0] = fr1; gw[1][1] = fr2; gw[1][2] = 0.f;
    }
    float acc = 0.f;
    for (int c = 0; c < 512; c++) {
        const float* xb = x + ((size_t)(n * 512 + c) << 12);
        const float* wb = w + (size_t)(c * 256 + o) * 9;
        float tmp[3][3];
#pragma unroll
        for (int dr = 0; dr < 3; dr++) tmp[dr][0] = tmp[dr][1] = tmp[dr][2] = 0.f;
        for (int dr = 0; dr < nh; dr++) {
            int r = rh[dr]; if (r < 0) continue;
            for (int ds = 0; ds < nw; ds++) {
                int s = cw[ds]; if (s < 0) continue;
                float xv = xb[(r << 6) + s];
                tmp[dr][0] += gw[ds][0] * xv;
                tmp[dr][1] += gw[ds][1] * xv;
                tmp[dr][2] += gw[ds][2] * xv;
            }
        }
#pragma unroll
        for (int a = 0; a < 3; a++) {
            float xg0 = 0.f, xg1 = 0.f, xg2 = 0.f;
            for (int dr = 0; dr < nh; dr++) {
                float g = gh[dr][a];
                xg0 += g * tmp[dr][0]; xg1 += g * tmp[dr][1]; xg2 += g * tmp[dr][2];
            }
            acc += xg0 * wb[a * 3] + xg1 * wb[a * 3 + 1] + xg2 * wb[a * 3 + 2];
        }
    }
    out[idx] = acc;
}

// ---------------------------------------------------------------- launch ----
extern "C" void kernel_launch(void* const* d_in, const int* in_sizes, int n_in,
                              void* d_out, int out_size, void* d_ws, size_t ws_size,
                              hipStream_t stream)
{
    (void)in_sizes; (void)n_in; (void)out_size;
    const float* x = (const float*)d_in[0];   // (16,512,64,64)
    const float* w = (const float*)d_in[1];   // (256,512,3,3)
    float* out = (float*)d_out;               // (16,256,128,128)

    const size_t need = (XP_ELEMS + WP_ELEMS + YP_ELEMS) * sizeof(__hip_bfloat16);
    if (ws_size >= need) {
        __hip_bfloat16* xp = (__hip_bfloat16*)d_ws;
        __hip_bfloat16* wp = xp + XP_ELEMS;
        __hip_bfloat16* yp = wp + WP_ELEMS;
        prep_kernel<<<dim3((int)(WP_ELEMS / 256)), dim3(256), 0, stream>>>(w, wp, xp);
        pack_x_kernel<<<dim3(64, 16), dim3(256), 0, stream>>>(x, xp);
        mfma_conv_kernel<<<dim3(4096), dim3(256), 0, stream>>>(xp, wp, yp);
        fir_kernel<<<dim3(4096), dim3(256), 0, stream>>>(yp, out);
    } else {
        fused_direct_kernel<<<dim3((int)(YP_ELEMS / 256)), dim3(256), 0, stream>>>(x, w, out);
    }
}

// Round 4
// 620.263 us; speedup vs baseline: 1.0950x; 1.0950x over previous
//
#include <hip/hip_runtime.h>
#include <hip/hip_bf16.h>

// ============================================================================
// UpConvsample2d via bf16 MFMA.
//
// Math (verified in round 1):
//   W1[c,o,a,b] = w[((c*256+o)*3+a)*3+b]
//   y1 parity planes p=(h'&1)*2+(w'&1), each 64x64 per (n,o):
//     ph=0 row taps: (r=i-1,a=2),(r=i,a=0)   ph=1: (r=i,a=1)   (cols same)
//   out = 3x3 FIR {0.4,1.2,0.4}^2 over y1 with top/left pad 2, crop 128x128.
//
// Phases:
//   1. prep: w -> wp[ab][o][c] bf16 + zero-pad row/col 0 of xp
//      pack_x: x -> xp[n][65][65][512] bf16, float4 global reads
//   2. mfma_conv: per parity, sum over taps of GEMM (M=spatial, N=o, K=c)
//      128x128 tile, 4 waves x (64x64), 16x16x32 bf16 MFMA, global_load_lds(16B)
//      r4: double-buffered LDS, T3-min 2-phase (stage next step before compute,
//      ONE barrier per K-step; compiler's pre-barrier vmcnt(0) drains stage).
//      r4: grid reverted to round-2 dim3(2,512,4) — r3 XCD chunking cut FETCH
//      6x but cost 70us (occupancy 31->18%); L3 already absorbed re-reads.
//   3. fir_kernel: per (n,o) plane, stage 4 parity planes in LDS (short8
//      coalesced), quad-pair per thread via 4B word reads, float4 stores.
// ============================================================================

typedef __attribute__((ext_vector_type(8))) short short8;
typedef __attribute__((ext_vector_type(4))) float float4v;

#define XP_ELEMS ((size_t)16 * 65 * 65 * 512)   // 34,611,200
#define WP_ELEMS ((size_t)9 * 256 * 512)        // 1,179,648
#define YP_ELEMS ((size_t)4 * 16 * 256 * 4096)  // 67,108,864

__device__ __forceinline__ void gl_lds16(const __hip_bfloat16* g, __hip_bfloat16* l) {
    __builtin_amdgcn_global_load_lds(
        (const __attribute__((address_space(1))) void*)g,
        (__attribute__((address_space(3))) void*)l, 16, 0, 0);
}

// --------------------------------------------------------------- prep -------
// idx < WP_ELEMS: pack w.  idx < 16*65*512: zero-pad xp row 0 / col 0.
__global__ __launch_bounds__(256) void prep_kernel(
    const float* __restrict__ w, __hip_bfloat16* __restrict__ wp,
    __hip_bfloat16* __restrict__ xp) {
    int idx = blockIdx.x * 256 + (int)threadIdx.x;  // 0 .. 9*256*512
    {   // ---- pack_w ----
        int c  = idx & 511;
        int o  = (idx >> 9) & 255;
        int ab = idx >> 17;                  // 0..8
        int a = ab / 3, b = ab % 3;
        wp[idx] = __float2bfloat16(w[((size_t)(c * 256 + o) * 3 + a) * 3 + b]);
    }
    if (idx < 16 * 65 * 512) {  // ---- zero-pad ----
        int c = idx & 511;
        int t = (idx >> 9) % 65;
        int n = idx / (65 * 512);
        __hip_bfloat16 z = __float2bfloat16(0.f);
        xp[(((size_t)(n * 65) + 0) * 65 + t) * 512 + c] = z;   // pad row 0
        xp[(((size_t)(n * 65) + t) * 65 + 0) * 512 + c] = z;   // pad col 0
    }
}

__global__ __launch_bounds__(256) void pack_x_kernel(
    const float* __restrict__ x, __hip_bfloat16* __restrict__ xp) {
    int i = blockIdx.x;       // 0..63
    int n = blockIdx.y;       // 0..15
    int tid = (int)threadIdx.x;
    __shared__ float tile[64][65];
    const int j4 = (tid & 15) * 4;
    for (int c0 = 0; c0 < 512; c0 += 64) {
        __syncthreads();
        // read: float4 per lane, 1KB per wave instr; 4 iters cover 64 ch x 64 j
#pragma unroll
        for (int rr = 0; rr < 4; rr++) {
            int cl = rr * 16 + (tid >> 4);
            float4v v = *(const float4v*)(
                x + (((size_t)(n * 512 + c0 + cl) * 64) + i) * 64 + j4);
#pragma unroll
            for (int t = 0; t < 4; t++) tile[cl][j4 + t] = v[t];
        }
        __syncthreads();
        // write: 512 tasks = 64 j x 8 channel-groups of 8; ushort8 stores
#pragma unroll
        for (int pass = 0; pass < 2; pass++) {
            int task = pass * 256 + tid;
            int j  = task >> 3;          // 0..63
            int cg = task & 7;           // channel group of 8
            union { short8 v; unsigned short h[8]; } u;
#pragma unroll
            for (int r = 0; r < 8; r++) {
                __hip_bfloat16 b = __float2bfloat16(tile[cg * 8 + r][j]);
                u.h[r] = *(unsigned short*)&b;
            }
            *(short8*)(xp + (((size_t)(n * 65) + i + 1) * 65 + (j + 1)) * 512 +
                       c0 + cg * 8) = u.v;
        }
    }
}

// ---------------------------------------------------------------- mfma conv -
// grid: (2 N-tiles, 512 M-tiles, 4 parities), block 256 (4 waves)
__global__ __launch_bounds__(256) void mfma_conv_kernel(
    const __hip_bfloat16* __restrict__ xp, const __hip_bfloat16* __restrict__ wp,
    __hip_bfloat16* __restrict__ yp) {
    const int p  = blockIdx.z, ph = p >> 1, pw = p & 1;
    const int o0 = blockIdx.x * 128;
    const int mt = blockIdx.y;
    const int n  = mt >> 5;
    const int i0 = (mt & 31) << 1;      // block covers rows i0, i0+1
    const int tid  = (int)threadIdx.x;
    const int wave = tid >> 6, lane = tid & 63;
    const int wm = wave & 1, wn = wave >> 1;
    const int lrow = lane & 15, quad = lane >> 4;
    const int m0j   = wave * 16 + (lane >> 2);   // A/B tile row this lane stages
    const int klane = (lane & 3) * 8;            // k element offset this lane stages

    // double-buffered: [buf][A 4096 | B 4096] bf16, 32KB total
    __shared__ __align__(16) __hip_bfloat16 lds[2 * 8192];

    float4v acc[4][4];
#pragma unroll
    for (int fm = 0; fm < 4; fm++)
#pragma unroll
        for (int fn = 0; fn < 4; fn++) acc[fm][fn] = (float4v)0.f;

    const int nrt = ph ? 1 : 2, nct = pw ? 1 : 2;
    const int nt  = nrt * nct;          // taps: 4 / 2 / 2 / 1

    // tap -> (rt, ct): row-major over (nrt, nct)
    auto mkA = [&](int tap) -> const __hip_bfloat16* {
        int rt = (nct == 2) ? (tap >> 1) : tap;
        int ct = (nct == 2) ? (tap & 1) : 0;
        int drp = ph ? 1 : rt;           // padded row offset
        int dsp = pw ? 1 : ct;
        return xp + (((size_t)(n * 65 + i0 + drp)) * 65 + m0j + dsp) * 512 + klane;
    };
    auto mkB = [&](int tap) -> const __hip_bfloat16* {
        int rt = (nct == 2) ? (tap >> 1) : tap;
        int ct = (nct == 2) ? (tap & 1) : 0;
        int a = ph ? 1 : (rt ? 0 : 2);
        int b = pw ? 1 : (ct ? 0 : 2);
        return wp + ((size_t)((a * 3 + b) * 256 + o0 + m0j)) * 512 + klane;
    };
    // never dereferenced unless tap < nt (pointer arithmetic only otherwise)
    const __hip_bfloat16* A0p = mkA(0); const __hip_bfloat16* B0p = mkB(0);
    const __hip_bfloat16* A1p = mkA(1); const __hip_bfloat16* B1p = mkB(1);
    const __hip_bfloat16* A2p = mkA(2); const __hip_bfloat16* B2p = mkB(2);
    const __hip_bfloat16* A3p = mkA(3); const __hip_bfloat16* B3p = mkB(3);

    const int nsteps = nt << 4;          // 16 K-steps (BK=32) per tap

    // prologue: stage step 0 into buf 0
    {
        __hip_bfloat16* dst = lds;
        gl_lds16(A0p,                     dst + wave * 512);
        gl_lds16(A0p + (size_t)65 * 512,  dst + 2048 + wave * 512);
        gl_lds16(B0p,                     dst + 4096 + wave * 512);
        gl_lds16(B0p + (size_t)64 * 512,  dst + 6144 + wave * 512);
    }
    __syncthreads();   // compiler drains vmcnt(0) before s_barrier

    for (int t = 0; t < nsteps; t++) {
        const int cb = t & 1;
        if (t + 1 < nsteps) {            // stage next step into other buffer
            const int tap = (t + 1) >> 4;
            const int c0  = ((t + 1) & 15) << 5;
            const __hip_bfloat16* At =
                (tap == 0) ? A0p : (tap == 1) ? A1p : (tap == 2) ? A2p : A3p;
            const __hip_bfloat16* Bt =
                (tap == 0) ? B0p : (tap == 1) ? B1p : (tap == 2) ? B2p : B3p;
            __hip_bfloat16* dst = lds + (cb ^ 1) * 8192;
            gl_lds16(At + c0,                    dst + wave * 512);
            gl_lds16(At + c0 + (size_t)65 * 512, dst + 2048 + wave * 512);
            gl_lds16(Bt + c0,                    dst + 4096 + wave * 512);
            gl_lds16(Bt + c0 + (size_t)64 * 512, dst + 6144 + wave * 512);
        }
        const __hip_bfloat16* src = lds + cb * 8192;
        short8 af[4], bv[4];
#pragma unroll
        for (int fm = 0; fm < 4; fm++)
            af[fm] = *(const short8*)(src + ((wm * 64 + fm * 16 + lrow) * 32 + quad * 8));
#pragma unroll
        for (int fn = 0; fn < 4; fn++)
            bv[fn] = *(const short8*)(src + 4096 + ((wn * 64 + fn * 16 + lrow) * 32 + quad * 8));
#pragma unroll
        for (int fm = 0; fm < 4; fm++)
#pragma unroll
            for (int fn = 0; fn < 4; fn++)
                acc[fm][fn] = __builtin_amdgcn_mfma_f32_16x16x32_bf16(
                    af[fm], bv[fn], acc[fm][fn], 0, 0, 0);
        __syncthreads();   // one barrier per K-step: drains stage + read-done
    }

    // epilogue: D row=(quad*4+reg) -> j, col=lrow -> o ; 4 consecutive j per lane
#pragma unroll
    for (int fm = 0; fm < 4; fm++) {
        int j0 = fm * 16 + quad * 4;
#pragma unroll
        for (int fn = 0; fn < 4; fn++) {
            int o = o0 + wn * 64 + fn * 16 + lrow;
            union { ushort4 v; __hip_bfloat16 h[4]; } u;
#pragma unroll
            for (int r = 0; r < 4; r++) u.h[r] = __float2bfloat16(acc[fm][fn][r]);
            *(ushort4*)(yp + (((size_t)(p * 4096 + n * 256 + o)) << 12) +
                        ((i0 + wm) << 6) + j0) = u.v;
        }
    }
}

// ---------------------------------------------------------------- FIR -------
// one block per (n,o) plane. Stage 4 parity planes (32KB) in LDS via short8,
// each thread computes a quad-pair (2 out rows x 4 out cols) per iteration.
__device__ __forceinline__ float bf_lo(unsigned u) { return __uint_as_float(u << 16); }
__device__ __forceinline__ float bf_hi(unsigned u) { return __uint_as_float(u & 0xffff0000u); }

__global__ __launch_bounds__(256) void fir_kernel(
    const __hip_bfloat16* __restrict__ yp, float* __restrict__ out) {
    const int no  = blockIdx.x;          // n*256 + o
    const int tid = (int)threadIdx.x;

    __shared__ __align__(16) unsigned short ylds[4 * 64 * 64];  // [q][ih][jw], 32KB

    // stage: 4 planes x 4096 bf16 = 2048 short8 chunks, fully coalesced
    const unsigned short* ysrc = (const unsigned short*)yp;
#pragma unroll
    for (int k = 0; k < 8; k++) {
        int chunk = k * 256 + tid;           // 0..2047
        int q   = chunk >> 9;                // 0..3
        int off = (chunk & 511) << 3;        // element offset in plane
        *(short8*)(ylds + q * 4096 + off) =
            *(const short8*)(ysrc + (((size_t)(q * 4096 + no)) << 12) + off);
    }
    __syncthreads();

    const unsigned* yw = (const unsigned*)ylds;  // word view: [q][ih][w], w=0..31

    const int qp = tid & 31;     // quad-pair: covers out cols 4qp..4qp+3
    const int iw = tid >> 5;     // 0..7

    // weight of plane-parity q, offset k, for output sub-parity e
    const float rw[2][2][2] = {{{0.4f, 0.4f}, {1.2f, 0.f}},
                               {{0.f, 1.2f}, {0.4f, 0.4f}}};  // [e][q][k]

    for (int s = 0; s < 8; s++) {
        const int I = s * 8 + iw;            // 0..63 (out rows 2I, 2I+1)

        // Y3[ph][pw][k][m]: cols {2qp-1, 2qp, 2qp+1} of plane (ph,pw), row I-1+k
        float Y3[2][2][2][3];
#pragma unroll
        for (int q = 0; q < 4; q++) {
            int phh = q >> 1, pww = q & 1;
#pragma unroll
            for (int k = 0; k < 2; k++) {
                int ih = I - 1 + k;
                float c0 = 0.f, c1 = 0.f, c2 = 0.f;
                if (ih >= 0) {
                    const unsigned* row = yw + (q * 64 + ih) * 32;
                    unsigned wb = row[qp];
                    c1 = bf_lo(wb);
                    c2 = bf_hi(wb);
                    if (qp > 0) c0 = bf_hi(row[qp - 1]);
                }
                Y3[phh][pww][k][0] = c0;
                Y3[phh][pww][k][1] = c1;
                Y3[phh][pww][k][2] = c2;
            }
        }

        float res[2][4];
#pragma unroll
        for (int t = 0; t < 2; t++) {        // quad t: J = 2qp+t, taps cols {t, t+1}
            float cs[2][2][2];               // [ph][k][ew]
#pragma unroll
            for (int phh = 0; phh < 2; phh++)
#pragma unroll
                for (int k = 0; k < 2; k++)
#pragma unroll
                    for (int ew = 0; ew < 2; ew++) {
                        float sv = 0.f;
#pragma unroll
                        for (int pww = 0; pww < 2; pww++)
#pragma unroll
                            for (int l = 0; l < 2; l++)
                                sv += rw[ew][pww][l] * Y3[phh][pww][k][t + l];
                        cs[phh][k][ew] = sv;
                    }
#pragma unroll
            for (int eh = 0; eh < 2; eh++)
#pragma unroll
                for (int ew = 0; ew < 2; ew++) {
                    float sv = 0.f;
#pragma unroll
                    for (int phh = 0; phh < 2; phh++)
#pragma unroll
                        for (int k = 0; k < 2; k++)
                            sv += rw[eh][phh][k] * cs[phh][k][ew];
                    res[eh][t * 2 + ew] = sv;
                }
        }

        size_t base = ((size_t)no << 14) + ((size_t)(2 * I) << 7) + 4 * qp;
        float4v v0 = {res[0][0], res[0][1], res[0][2], res[0][3]};
        float4v v1 = {res[1][0], res[1][1], res[1][2], res[1][3]};
        *(float4v*)(out + base)       = v0;
        *(float4v*)(out + base + 128) = v1;
    }
}

// ------------------------------------------------- fallback (ws too small) --
__global__ __launch_bounds__(256) void fused_direct_kernel(
    const float* __restrict__ x, const float* __restrict__ w,
    float* __restrict__ out) {
    int idx = blockIdx.x * 256 + (int)threadIdx.x;
    int w_ = idx & 127, h = (idx >> 7) & 127, no = idx >> 14;
    int o = no & 255, n = no >> 8;
    int I = h >> 1, J = w_ >> 1;
    const float fr0 = 0.4f, fr1 = 1.2f, fr2 = 0.4f;
    float gh[3][3]; int rh[3]; int nh;
    if ((h & 1) == 0) {
        nh = 3;
        rh[0] = I - 2; gh[0][0] = 0.f; gh[0][1] = 0.f; gh[0][2] = fr0;
        rh[1] = I - 1; gh[1][0] = fr0; gh[1][1] = fr1; gh[1][2] = fr2;
        rh[2] = I;     gh[2][0] = fr2; gh[2][1] = 0.f; gh[2][2] = 0.f;
    } else {
        nh = 2;
        rh[0] = I - 1; gh[0][0] = 0.f; gh[0][1] = fr0; gh[0][2] = fr1;
        rh[1] = I;     gh[1][0] = fr1; gh[1][1] = fr2; gh[1][2] = 0.f;
    }
    float gw[3][3]; int cw[3]; int nw;
    if ((w_ & 1) == 0) {
        nw = 3;
        cw[0] = J - 2; gw[0][0] = 0.f; gw[0][1] = 0.f; gw[0][2] = fr0;
        cw[1] = J - 1; gw[1][0] = fr0; gw[1][1] = fr1; gw[1][2] = fr2;
        cw[2] = J;     gw[2][0] = fr2; gw[2][1] = 0.f; gw[2][2] = 0.f;
    } else {
        nw = 2;
        cw[0] = J - 1; gw[0][0] = 0.f; gw[0][1] = fr0; gw[0][2] = fr1;
        cw[1] = J;     gw[1][0] = fr1; gw[1][1] = fr2; gw[1][2] = 0.f;
    }
    float acc = 0.f;
    for (int c = 0; c < 512; c++) {
        const float* xb = x + ((size_t)(n * 512 + c) << 12);
        const float* wb = w + (size_t)(c * 256 + o) * 9;
        float tmp[3][3];
#pragma unroll
        for (int dr = 0; dr < 3; dr++) tmp[dr][0] = tmp[dr][1] = tmp[dr][2] = 0.f;
        for (int dr = 0; dr < nh; dr++) {
            int r = rh[dr]; if (r < 0) continue;
            for (int ds = 0; ds < nw; ds++) {
                int s = cw[ds]; if (s < 0) continue;
                float xv = xb[(r << 6) + s];
                tmp[dr][0] += gw[ds][0] * xv;
                tmp[dr][1] += gw[ds][1] * xv;
                tmp[dr][2] += gw[ds][2] * xv;
            }
        }
#pragma unroll
        for (int a = 0; a < 3; a++) {
            float xg0 = 0.f, xg1 = 0.f, xg2 = 0.f;
            for (int dr = 0; dr < nh; dr++) {
                float g = gh[dr][a];
                xg0 += g * tmp[dr][0]; xg1 += g * tmp[dr][1]; xg2 += g * tmp[dr][2];
            }
            acc += xg0 * wb[a * 3] + xg1 * wb[a * 3 + 1] + xg2 * wb[a * 3 + 2];
        }
    }
    out[idx] = acc;
}

// ---------------------------------------------------------------- launch ----
extern "C" void kernel_launch(void* const* d_in, const int* in_sizes, int n_in,
                              void* d_out, int out_size, void* d_ws, size_t ws_size,
                              hipStream_t stream)
{
    (void)in_sizes; (void)n_in; (void)out_size;
    const float* x = (const float*)d_in[0];   // (16,512,64,64)
    const float* w = (const float*)d_in[1];   // (256,512,3,3)
    float* out = (float*)d_out;               // (16,256,128,128)

    const size_t need = (XP_ELEMS + WP_ELEMS + YP_ELEMS) * sizeof(__hip_bfloat16);
    if (ws_size >= need) {
        __hip_bfloat16* xp = (__hip_bfloat16*)d_ws;
        __hip_bfloat16* wp = xp + XP_ELEMS;
        __hip_bfloat16* yp = wp + WP_ELEMS;
        prep_kernel<<<dim3((int)(WP_ELEMS / 256)), dim3(256), 0, stream>>>(w, wp, xp);
        pack_x_kernel<<<dim3(64, 16), dim3(256), 0, stream>>>(x, xp);
        mfma_conv_kernel<<<dim3(2, 512, 4), dim3(256), 0, stream>>>(xp, wp, yp);
        fir_kernel<<<dim3(4096), dim3(256), 0, stream>>>(yp, out);
    } else {
        fused_direct_kernel<<<dim3((int)(YP_ELEMS / 256)), dim3(256), 0, stream>>>(x, w, out);
    }
}

// Round 6
// 594.407 us; speedup vs baseline: 1.1426x; 1.0435x over previous
//
#include <hip/hip_runtime.h>
#include <hip/hip_bf16.h>

// ============================================================================
// UpConvsample2d via bf16 MFMA.
//
// Math (verified in round 1):
//   W1[c,o,a,b] = w[((c*256+o)*3+a)*3+b]
//   y1 parity planes p=(h'&1)*2+(w'&1), each 64x64 per (n,o):
//     ph=0 row taps: (r=i-1,a=2),(r=i,a=0)   ph=1: (r=i,a=1)   (cols same)
//   out = 3x3 FIR {0.4,1.2,0.4}^2 over y1 with top/left pad 2, crop 128x128.
//
// Phases:
//   1. prep: w -> wp[ab][o][c] bf16 + zero-pad row/col 0 of xp
//      pack_x: x -> xp[n][65][65][512] bf16, float4 global reads
//   2. mfma_conv (r5 restructure): c0 OUTER, taps INNER. Per K-step stage the
//      A-UNION once ([xi 0..2][jj 0..64][32], 195 rows, 4 gl_lds16) + per-tap
//      B tiles; compute ALL taps from the one A buffer via shifted LDS reads.
//      p=0: 64 MFMA per barrier-pair (was 16), 4x fewer vmcnt(0) drains,
//      A-staging traffic halved. LDS 48KB single-buffer, 3 blocks/CU.
//      (r4 dbuf was neutral -> drains amortize only via more MFMA/step.)
//   3. fir_kernel: per (n,o) plane, stage 4 parity planes in LDS (short8
//      coalesced), quad-pair per thread via 4B word reads, float4 stores.
// ============================================================================

typedef __attribute__((ext_vector_type(8))) short short8;
typedef __attribute__((ext_vector_type(4))) float float4v;

#define XP_ELEMS ((size_t)16 * 65 * 65 * 512)   // 34,611,200
#define WP_ELEMS ((size_t)9 * 256 * 512)        // 1,179,648
#define YP_ELEMS ((size_t)4 * 16 * 256 * 4096)  // 67,108,864

__device__ __forceinline__ void gl_lds16(const __hip_bfloat16* g, __hip_bfloat16* l) {
    __builtin_amdgcn_global_load_lds(
        (const __attribute__((address_space(1))) void*)g,
        (__attribute__((address_space(3))) void*)l, 16, 0, 0);
}

// --------------------------------------------------------------- prep -------
// idx < WP_ELEMS: pack w.  idx < 16*65*512: zero-pad xp row 0 / col 0.
__global__ __launch_bounds__(256) void prep_kernel(
    const float* __restrict__ w, __hip_bfloat16* __restrict__ wp,
    __hip_bfloat16* __restrict__ xp) {
    int idx = blockIdx.x * 256 + (int)threadIdx.x;  // 0 .. 9*256*512
    {   // ---- pack_w ----
        int c  = idx & 511;
        int o  = (idx >> 9) & 255;
        int ab = idx >> 17;                  // 0..8
        int a = ab / 3, b = ab % 3;
        wp[idx] = __float2bfloat16(w[((size_t)(c * 256 + o) * 3 + a) * 3 + b]);
    }
    if (idx < 16 * 65 * 512) {  // ---- zero-pad ----
        int c = idx & 511;
        int t = (idx >> 9) % 65;
        int n = idx / (65 * 512);
        __hip_bfloat16 z = __float2bfloat16(0.f);
        xp[(((size_t)(n * 65) + 0) * 65 + t) * 512 + c] = z;   // pad row 0
        xp[(((size_t)(n * 65) + t) * 65 + 0) * 512 + c] = z;   // pad col 0
    }
}

__global__ __launch_bounds__(256) void pack_x_kernel(
    const float* __restrict__ x, __hip_bfloat16* __restrict__ xp) {
    int i = blockIdx.x;       // 0..63
    int n = blockIdx.y;       // 0..15
    int tid = (int)threadIdx.x;
    __shared__ float tile[64][65];
    const int j4 = (tid & 15) * 4;
    for (int c0 = 0; c0 < 512; c0 += 64) {
        __syncthreads();
        // read: float4 per lane, 1KB per wave instr; 4 iters cover 64 ch x 64 j
#pragma unroll
        for (int rr = 0; rr < 4; rr++) {
            int cl = rr * 16 + (tid >> 4);
            float4v v = *(const float4v*)(
                x + (((size_t)(n * 512 + c0 + cl) * 64) + i) * 64 + j4);
#pragma unroll
            for (int t = 0; t < 4; t++) tile[cl][j4 + t] = v[t];
        }
        __syncthreads();
        // write: 512 tasks = 64 j x 8 channel-groups of 8; ushort8 stores
#pragma unroll
        for (int pass = 0; pass < 2; pass++) {
            int task = pass * 256 + tid;
            int j  = task >> 3;          // 0..63
            int cg = task & 7;           // channel group of 8
            union { short8 v; unsigned short h[8]; } u;
#pragma unroll
            for (int r = 0; r < 8; r++) {
                __hip_bfloat16 b = __float2bfloat16(tile[cg * 8 + r][j]);
                u.h[r] = *(unsigned short*)&b;
            }
            *(short8*)(xp + (((size_t)(n * 65) + i + 1) * 65 + (j + 1)) * 512 +
                       c0 + cg * 8) = u.v;
        }
    }
}

// ---------------------------------------------------------------- mfma conv -
// grid: (2 N-tiles, 512 M-tiles, 4 parities), block 256 (4 waves)
// LDS: A-union [row = xi*65+jj][32] bf16 (195 rows used, staged as 256) +
//      B [tap slot 0..3][128 o-rows][32].  Single buffer, 2 barriers / K-step.
__global__ __launch_bounds__(256, 3) void mfma_conv_kernel(
    const __hip_bfloat16* __restrict__ xp, const __hip_bfloat16* __restrict__ wp,
    __hip_bfloat16* __restrict__ yp) {
    const int p  = blockIdx.z, ph = p >> 1, pw = p & 1;
    const int o0 = blockIdx.x * 128;
    const int mt = blockIdx.y;
    const int n  = mt >> 5;
    const int i0 = (mt & 31) << 1;      // block covers rows i0, i0+1
    const int tid  = (int)threadIdx.x;
    const int wave = tid >> 6, lane = tid & 63;
    const int wm = wave & 1, wn = wave >> 1;
    const int lrow = lane & 15, quad = lane >> 4;
    const int m0j   = wave * 16 + (lane >> 2);   // B tile row this lane stages
    const int klane = (lane & 3) * 8;            // k element offset this lane stages

    __shared__ __align__(16) __hip_bfloat16 lA[256 * 32];       // 16KB
    __shared__ __align__(16) __hip_bfloat16 lB[4 * 128 * 32];   // 32KB

    float4v acc[4][4];
#pragma unroll
    for (int fm = 0; fm < 4; fm++)
#pragma unroll
        for (int fn = 0; fn < 4; fn++) acc[fm][fn] = (float4v)0.f;

    const int nct = pw ? 1 : 2;
    const int nt  = (ph ? 1 : 2) * nct;          // taps: 4 / 2 / 2 / 1

    // ---- A-union staging source offsets: call k stages LDS rows [64k,64k+64)
    // row R = xi*65+jj holds xp[n][i0+xi][jj][k-slice]; R>=195 clamped (safe dup)
    const __hip_bfloat16* bA = xp + (size_t)n * 65 * 65 * 512;
    const int Rb = (wave << 4) + (lane >> 2);    // 0..63, this lane's base row
    int offA0, offA1, offA2, offA3;
    {
        int R0 = Rb, R1 = Rb + 64, R2 = Rb + 128, R3 = Rb + 192;
        if (R3 > 194) R3 = 194;
        offA0 = ((i0 + R0 / 65) * 65 + R0 % 65) * 512 + klane;
        offA1 = ((i0 + R1 / 65) * 65 + R1 % 65) * 512 + klane;
        offA2 = ((i0 + R2 / 65) * 65 + R2 % 65) * 512 + klane;
        offA3 = ((i0 + R3 / 65) * 65 + R3 % 65) * 512 + klane;
    }
    const __hip_bfloat16* bB = wp + (size_t)(o0 + m0j) * 512 + klane;

    // ---- per-tap constants (tap t -> (rt,ct) row-major over (nrt,nct)) ----
    // tap0: (0,0); tap1: nct==2 ? (0,1) : (1,0); tap2: (1,0); tap3: (1,1)
    const int rt1 = (nct == 2) ? 0 : 1, ct1 = (nct == 2) ? 1 : 0;
    const int aoffL = lrow * 32 + quad * 8;
    // A LDS offset: ((drp+wm)*65 + dsp)*32 + aoffL ; af[fm] at +fm*512
    const int aoff0 = ((ph ? 1 : 0)   + wm) * 2080 + (pw ? 1 : 0)   * 32 + aoffL;
    const int aoff1 = ((ph ? 1 : rt1) + wm) * 2080 + (pw ? 1 : ct1) * 32 + aoffL;
    const int aoff2 = ((ph ? 1 : 1)   + wm) * 2080 + (pw ? 1 : 0)   * 32 + aoffL;
    const int aoff3 = ((ph ? 1 : 1)   + wm) * 2080 + (pw ? 1 : 1)   * 32 + aoffL;
    // B matrix index ab = a*3+b, scaled to elems (256*512)
    const int ab0 = ((ph ? 1 : 2) * 3 + (pw ? 1 : 2)) * 131072;
    const int ab1 = ((ph ? 1 : (rt1 ? 0 : 2)) * 3 + (pw ? 1 : (ct1 ? 0 : 2))) * 131072;
    const int ab2 = ((ph ? 1 : 0) * 3 + (pw ? 1 : 2)) * 131072;
    const int ab3 = ((ph ? 1 : 0) * 3 + (pw ? 1 : 0)) * 131072;

    const int boff = (wn * 64 + lrow) * 32 + quad * 8;

    auto compute_tap = [&](int aoffT, const __hip_bfloat16* lBt) {
        short8 af[4], bv[4];
#pragma unroll
        for (int fm = 0; fm < 4; fm++)
            af[fm] = *(const short8*)(lA + aoffT + fm * 512);
#pragma unroll
        for (int fn = 0; fn < 4; fn++)
            bv[fn] = *(const short8*)(lBt + boff + fn * 512);
#pragma unroll
        for (int fm = 0; fm < 4; fm++)
#pragma unroll
            for (int fn = 0; fn < 4; fn++)
                acc[fm][fn] = __builtin_amdgcn_mfma_f32_16x16x32_bf16(
                    af[fm], bv[fn], acc[fm][fn], 0, 0, 0);
    };

    for (int c0 = 0; c0 < 512; c0 += 32) {
        __syncthreads();                         // prior reads done, overwrite ok
        gl_lds16(bA + offA0 + c0, lA +        wave * 512);
        gl_lds16(bA + offA1 + c0, lA + 2048 + wave * 512);
        gl_lds16(bA + offA2 + c0, lA + 4096 + wave * 512);
        gl_lds16(bA + offA3 + c0, lA + 6144 + wave * 512);
        gl_lds16(bB + (ab0 + c0),         lB +        wave * 512);
        gl_lds16(bB + (ab0 + 32768 + c0), lB + 2048 + wave * 512);
        if (nt > 1) {
            gl_lds16(bB + (ab1 + c0),         lB + 4096 + wave * 512);
            gl_lds16(bB + (ab1 + 32768 + c0), lB + 6144 + wave * 512);
        }
        if (nt > 2) {
            gl_lds16(bB + (ab2 + c0),         lB + 8192  + wave * 512);
            gl_lds16(bB + (ab2 + 32768 + c0), lB + 10240 + wave * 512);
            gl_lds16(bB + (ab3 + c0),         lB + 12288 + wave * 512);
            gl_lds16(bB + (ab3 + 32768 + c0), lB + 14336 + wave * 512);
        }
        __syncthreads();                         // stage drained (vmcnt0 + bar)
        compute_tap(aoff0, lB);
        if (nt > 1) compute_tap(aoff1, lB + 4096);
        if (nt > 2) {
            compute_tap(aoff2, lB + 8192);
            compute_tap(aoff3, lB + 12288);
        }
    }

    // epilogue: D row=(quad*4+reg) -> j, col=lrow -> o ; 4 consecutive j per lane
#pragma unroll
    for (int fm = 0; fm < 4; fm++) {
        int j0 = fm * 16 + quad * 4;
#pragma unroll
        for (int fn = 0; fn < 4; fn++) {
            int o = o0 + wn * 64 + fn * 16 + lrow;
            union { ushort4 v; __hip_bfloat16 h[4]; } u;
#pragma unroll
            for (int r = 0; r < 4; r++) u.h[r] = __float2bfloat16(acc[fm][fn][r]);
            *(ushort4*)(yp + (((size_t)(p * 4096 + n * 256 + o)) << 12) +
                        ((i0 + wm) << 6) + j0) = u.v;
        }
    }
}

// ---------------------------------------------------------------- FIR -------
// one block per (n,o) plane. Stage 4 parity planes (32KB) in LDS via short8,
// each thread computes a quad-pair (2 out rows x 4 out cols) per iteration.
__device__ __forceinline__ float bf_lo(unsigned u) { return __uint_as_float(u << 16); }
__device__ __forceinline__ float bf_hi(unsigned u) { return __uint_as_float(u & 0xffff0000u); }

__global__ __launch_bounds__(256) void fir_kernel(
    const __hip_bfloat16* __restrict__ yp, float* __restrict__ out) {
    const int no  = blockIdx.x;          // n*256 + o
    const int tid = (int)threadIdx.x;

    __shared__ __align__(16) unsigned short ylds[4 * 64 * 64];  // [q][ih][jw], 32KB

    // stage: 4 planes x 4096 bf16 = 2048 short8 chunks, fully coalesced
    const unsigned short* ysrc = (const unsigned short*)yp;
#pragma unroll
    for (int k = 0; k < 8; k++) {
        int chunk = k * 256 + tid;           // 0..2047
        int q   = chunk >> 9;                // 0..3
        int off = (chunk & 511) << 3;        // element offset in plane
        *(short8*)(ylds + q * 4096 + off) =
            *(const short8*)(ysrc + (((size_t)(q * 4096 + no)) << 12) + off);
    }
    __syncthreads();

    const unsigned* yw = (const unsigned*)ylds;  // word view: [q][ih][w], w=0..31

    const int qp = tid & 31;     // quad-pair: covers out cols 4qp..4qp+3
    const int iw = tid >> 5;     // 0..7

    // weight of plane-parity q, offset k, for output sub-parity e
    const float rw[2][2][2] = {{{0.4f, 0.4f}, {1.2f, 0.f}},
                               {{0.f, 1.2f}, {0.4f, 0.4f}}};  // [e][q][k]

    for (int s = 0; s < 8; s++) {
        const int I = s * 8 + iw;            // 0..63 (out rows 2I, 2I+1)

        // Y3[ph][pw][k][m]: cols {2qp-1, 2qp, 2qp+1} of plane (ph,pw), row I-1+k
        float Y3[2][2][2][3];
#pragma unroll
        for (int q = 0; q < 4; q++) {
            int phh = q >> 1, pww = q & 1;
#pragma unroll
            for (int k = 0; k < 2; k++) {
                int ih = I - 1 + k;
                float c0 = 0.f, c1 = 0.f, c2 = 0.f;
                if (ih >= 0) {
                    const unsigned* row = yw + (q * 64 + ih) * 32;
                    unsigned wb = row[qp];
                    c1 = bf_lo(wb);
                    c2 = bf_hi(wb);
                    if (qp > 0) c0 = bf_hi(row[qp - 1]);
                }
                Y3[phh][pww][k][0] = c0;
                Y3[phh][pww][k][1] = c1;
                Y3[phh][pww][k][2] = c2;
            }
        }

        float res[2][4];
#pragma unroll
        for (int t = 0; t < 2; t++) {        // quad t: J = 2qp+t, taps cols {t, t+1}
            float cs[2][2][2];               // [ph][k][ew]
#pragma unroll
            for (int phh = 0; phh < 2; phh++)
#pragma unroll
                for (int k = 0; k < 2; k++)
#pragma unroll
                    for (int ew = 0; ew < 2; ew++) {
                        float sv = 0.f;
#pragma unroll
                        for (int pww = 0; pww < 2; pww++)
#pragma unroll
                            for (int l = 0; l < 2; l++)
                                sv += rw[ew][pww][l] * Y3[phh][pww][k][t + l];
                        cs[phh][k][ew] = sv;
                    }
#pragma unroll
            for (int eh = 0; eh < 2; eh++)
#pragma unroll
                for (int ew = 0; ew < 2; ew++) {
                    float sv = 0.f;
#pragma unroll
                    for (int phh = 0; phh < 2; phh++)
#pragma unroll
                        for (int k = 0; k < 2; k++)
                            sv += rw[eh][phh][k] * cs[phh][k][ew];
                    res[eh][t * 2 + ew] = sv;
                }
        }

        size_t base = ((size_t)no << 14) + ((size_t)(2 * I) << 7) + 4 * qp;
        float4v v0 = {res[0][0], res[0][1], res[0][2], res[0][3]};
        float4v v1 = {res[1][0], res[1][1], res[1][2], res[1][3]};
        *(float4v*)(out + base)       = v0;
        *(float4v*)(out + base + 128) = v1;
    }
}

// ------------------------------------------------- fallback (ws too small) --
__global__ __launch_bounds__(256) void fused_direct_kernel(
    const float* __restrict__ x, const float* __restrict__ w,
    float* __restrict__ out) {
    int idx = blockIdx.x * 256 + (int)threadIdx.x;
    int w_ = idx & 127, h = (idx >> 7) & 127, no = idx >> 14;
    int o = no & 255, n = no >> 8;
    int I = h >> 1, J = w_ >> 1;
    const float fr0 = 0.4f, fr1 = 1.2f, fr2 = 0.4f;
    float gh[3][3]; int rh[3]; int nh;
    if ((h & 1) == 0) {
        nh = 3;
        rh[0] = I - 2; gh[0][0] = 0.f; gh[0][1] = 0.f; gh[0][2] = fr0;
        rh[1] = I - 1; gh[1][0] = fr0; gh[1][1] = fr1; gh[1][2] = fr2;
        rh[2] = I;     gh[2][0] = fr2; gh[2][1] = 0.f; gh[2][2] = 0.f;
    } else {
        nh = 2;
        rh[0] = I - 1; gh[0][0] = 0.f; gh[0][1] = fr0; gh[0][2] = fr1;
        rh[1] = I;     gh[1][0] = fr1; gh[1][1] = fr2; gh[1][2] = 0.f;
    }
    float gw[3][3]; int cw[3]; int nw;
    if ((w_ & 1) == 0) {
        nw = 3;
        cw[0] = J - 2; gw[0][0] = 0.f; gw[0][1] = 0.f; gw[0][2] = fr0;
        cw[1] = J - 1; gw[1][0] = fr0; gw[1][1] = fr1; gw[1][2] = fr2;
        cw[2] = J;     gw[2][0] = fr2; gw[2][1] = 0.f; gw[2][2] = 0.f;
    } else {
        nw = 2;
        cw[0] = J - 1; gw[0][0] = 0.f; gw[0][1] = fr0; gw[0][2] = fr1;
        cw[1] = J;     gw[1][0] = fr1; gw[1][1] = fr2; gw[1][2] = 0.f;
    }
    float acc = 0.f;
    for (int c = 0; c < 512; c++) {
        const float* xb = x + ((size_t)(n * 512 + c) << 12);
        const float* wb = w + (size_t)(c * 256 + o) * 9;
        float tmp[3][3];
#pragma unroll
        for (int dr = 0; dr < 3; dr++) tmp[dr][0] = tmp[dr][1] = tmp[dr][2] = 0.f;
        for (int dr = 0; dr < nh; dr++) {
            int r = rh[dr]; if (r < 0) continue;
            for (int ds = 0; ds < nw; ds++) {
                int s = cw[ds]; if (s < 0) continue;
                float xv = xb[(r << 6) + s];
                tmp[dr][0] += gw[ds][0] * xv;
                tmp[dr][1] += gw[ds][1] * xv;
                tmp[dr][2] += gw[ds][2] * xv;
            }
        }
#pragma unroll
        for (int a = 0; a < 3; a++) {
            float xg0 = 0.f, xg1 = 0.f, xg2 = 0.f;
            for (int dr = 0; dr < nh; dr++) {
                float g = gh[dr][a];
                xg0 += g * tmp[dr][0]; xg1 += g * tmp[dr][1]; xg2 += g * tmp[dr][2];
            }
            acc += xg0 * wb[a * 3] + xg1 * wb[a * 3 + 1] + xg2 * wb[a * 3 + 2];
        }
    }
    out[idx] = acc;
}

// ---------------------------------------------------------------- launch ----
extern "C" void kernel_launch(void* const* d_in, const int* in_sizes, int n_in,
                              void* d_out, int out_size, void* d_ws, size_t ws_size,
                              hipStream_t stream)
{
    (void)in_sizes; (void)n_in; (void)out_size;
    const float* x = (const float*)d_in[0];   // (16,512,64,64)
    const float* w = (const float*)d_in[1];   // (256,512,3,3)
    float* out = (float*)d_out;               // (16,256,128,128)

    const size_t need = (XP_ELEMS + WP_ELEMS + YP_ELEMS) * sizeof(__hip_bfloat16);
    if (ws_size >= need) {
        __hip_bfloat16* xp = (__hip_bfloat16*)d_ws;
        __hip_bfloat16* wp = xp + XP_ELEMS;
        __hip_bfloat16* yp = wp + WP_ELEMS;
        prep_kernel<<<dim3((int)(WP_ELEMS / 256)), dim3(256), 0, stream>>>(w, wp, xp);
        pack_x_kernel<<<dim3(64, 16), dim3(256), 0, stream>>>(x, xp);
        mfma_conv_kernel<<<dim3(2, 512, 4), dim3(256), 0, stream>>>(xp, wp, yp);
        fir_kernel<<<dim3(4096), dim3(256), 0, stream>>>(yp, out);
    } else {
        fused_direct_kernel<<<dim3((int)(YP_ELEMS / 256)), dim3(256), 0, stream>>>(x, w, out);
    }
}

// Round 8
// 591.941 us; speedup vs baseline: 1.1474x; 1.0042x over previous
//
#include <hip/hip_runtime.h>
#include <hip/hip_bf16.h>

// ============================================================================
// UpConvsample2d via bf16 MFMA.
//
// Math (verified in round 1):
//   W1[c,o,a,b] = w[((c*256+o)*3+a)*3+b]
//   y1 parity planes p=(h'&1)*2+(w'&1), each 64x64 per (n,o):
//     ph=0 row taps: (r=i-1,a=2),(r=i,a=0)   ph=1: (r=i,a=1)   (cols same)
//   out = 3x3 FIR {0.4,1.2,0.4}^2 over y1 with top/left pad 2, crop 128x128.
//
// Phases:
//   1. prep: w -> wp[ab][o][c] bf16 + zero-pad row/col 0 of xp
//      pack_x: x -> xp[n][65][65][512] bf16, float4 reads; r7: grid split by
//      channel-half (2048 blocks, 8/CU) for latency hiding.
//   2. mfma_conv (r5/r6, UNTOUCHED this round): c0 outer, taps inner, A-union
//      staged once per K-step, 64 MFMA per barrier-pair at p=0. 202us, 33% MFMA.
//   3. fir_kernel; r7: split per (n,o) plane into 2 row-halves + 1-row halo in
//      LDS slot 0 -> 16.9KB LDS (9 blocks/CU), 8192 blocks. Same math/vecs.
//      (r7 is a TLP experiment on the constant ~392us non-mfma residual.)
// ============================================================================

typedef __attribute__((ext_vector_type(8))) short short8;
typedef __attribute__((ext_vector_type(4))) float float4v;

#define XP_ELEMS ((size_t)16 * 65 * 65 * 512)   // 34,611,200
#define WP_ELEMS ((size_t)9 * 256 * 512)        // 1,179,648
#define YP_ELEMS ((size_t)4 * 16 * 256 * 4096)  // 67,108,864

__device__ __forceinline__ void gl_lds16(const __hip_bfloat16* g, __hip_bfloat16* l) {
    __builtin_amdgcn_global_load_lds(
        (const __attribute__((address_space(1))) void*)g,
        (__attribute__((address_space(3))) void*)l, 16, 0, 0);
}

// --------------------------------------------------------------- prep -------
// idx < WP_ELEMS: pack w.  idx < 16*65*512: zero-pad xp row 0 / col 0.
__global__ __launch_bounds__(256) void prep_kernel(
    const float* __restrict__ w, __hip_bfloat16* __restrict__ wp,
    __hip_bfloat16* __restrict__ xp) {
    int idx = blockIdx.x * 256 + (int)threadIdx.x;  // 0 .. 9*256*512
    {   // ---- pack_w ----
        int c  = idx & 511;
        int o  = (idx >> 9) & 255;
        int ab = idx >> 17;                  // 0..8
        int a = ab / 3, b = ab % 3;
        wp[idx] = __float2bfloat16(w[((size_t)(c * 256 + o) * 3 + a) * 3 + b]);
    }
    if (idx < 16 * 65 * 512) {  // ---- zero-pad ----
        int c = idx & 511;
        int t = (idx >> 9) % 65;
        int n = idx / (65 * 512);
        __hip_bfloat16 z = __float2bfloat16(0.f);
        xp[(((size_t)(n * 65) + 0) * 65 + t) * 512 + c] = z;   // pad row 0
        xp[(((size_t)(n * 65) + t) * 65 + 0) * 512 + c] = z;   // pad col 0
    }
}

// grid (64 i, 16 n, 2 channel-halves), block 256
__global__ __launch_bounds__(256) void pack_x_kernel(
    const float* __restrict__ x, __hip_bfloat16* __restrict__ xp) {
    int i = blockIdx.x;       // 0..63
    int n = blockIdx.y;       // 0..15
    int ch = blockIdx.z;      // 0..1 channel half
    int tid = (int)threadIdx.x;
    __shared__ float tile[64][65];
    const int j4 = (tid & 15) * 4;
    for (int cc = 0; cc < 4; cc++) {
        int c0 = ch * 256 + cc * 64;
        __syncthreads();
        // read: float4 per lane; 4 iters cover 64 ch x 64 j
#pragma unroll
        for (int rr = 0; rr < 4; rr++) {
            int cl = rr * 16 + (tid >> 4);
            float4v v = *(const float4v*)(
                x + (((size_t)(n * 512 + c0 + cl) * 64) + i) * 64 + j4);
#pragma unroll
            for (int t = 0; t < 4; t++) tile[cl][j4 + t] = v[t];
        }
        __syncthreads();
        // write: 512 tasks = 64 j x 8 channel-groups of 8; ushort8 stores
#pragma unroll
        for (int pass = 0; pass < 2; pass++) {
            int task = pass * 256 + tid;
            int j  = task >> 3;          // 0..63
            int cg = task & 7;           // channel group of 8
            union { short8 v; unsigned short h[8]; } u;
#pragma unroll
            for (int r = 0; r < 8; r++) {
                __hip_bfloat16 b = __float2bfloat16(tile[cg * 8 + r][j]);
                u.h[r] = *(unsigned short*)&b;
            }
            *(short8*)(xp + (((size_t)(n * 65) + i + 1) * 65 + (j + 1)) * 512 +
                       c0 + cg * 8) = u.v;
        }
    }
}

// ---------------------------------------------------------------- mfma conv -
// grid: (2 N-tiles, 512 M-tiles, 4 parities), block 256 (4 waves)
// LDS: A-union [row = xi*65+jj][32] bf16 (195 rows used, staged as 256) +
//      B [tap slot 0..3][128 o-rows][32].  Single buffer, 2 barriers / K-step.
__global__ __launch_bounds__(256, 3) void mfma_conv_kernel(
    const __hip_bfloat16* __restrict__ xp, const __hip_bfloat16* __restrict__ wp,
    __hip_bfloat16* __restrict__ yp) {
    const int p  = blockIdx.z, ph = p >> 1, pw = p & 1;
    const int o0 = blockIdx.x * 128;
    const int mt = blockIdx.y;
    const int n  = mt >> 5;
    const int i0 = (mt & 31) << 1;      // block covers rows i0, i0+1
    const int tid  = (int)threadIdx.x;
    const int wave = tid >> 6, lane = tid & 63;
    const int wm = wave & 1, wn = wave >> 1;
    const int lrow = lane & 15, quad = lane >> 4;
    const int m0j   = wave * 16 + (lane >> 2);   // B tile row this lane stages
    const int klane = (lane & 3) * 8;            // k element offset this lane stages

    __shared__ __align__(16) __hip_bfloat16 lA[256 * 32];       // 16KB
    __shared__ __align__(16) __hip_bfloat16 lB[4 * 128 * 32];   // 32KB

    float4v acc[4][4];
#pragma unroll
    for (int fm = 0; fm < 4; fm++)
#pragma unroll
        for (int fn = 0; fn < 4; fn++) acc[fm][fn] = (float4v)0.f;

    const int nct = pw ? 1 : 2;
    const int nt  = (ph ? 1 : 2) * nct;          // taps: 4 / 2 / 2 / 1

    // ---- A-union staging source offsets: call k stages LDS rows [64k,64k+64)
    // row R = xi*65+jj holds xp[n][i0+xi][jj][k-slice]; R>=195 clamped (safe dup)
    const __hip_bfloat16* bA = xp + (size_t)n * 65 * 65 * 512;
    const int Rb = (wave << 4) + (lane >> 2);    // 0..63, this lane's base row
    int offA0, offA1, offA2, offA3;
    {
        int R0 = Rb, R1 = Rb + 64, R2 = Rb + 128, R3 = Rb + 192;
        if (R3 > 194) R3 = 194;
        offA0 = ((i0 + R0 / 65) * 65 + R0 % 65) * 512 + klane;
        offA1 = ((i0 + R1 / 65) * 65 + R1 % 65) * 512 + klane;
        offA2 = ((i0 + R2 / 65) * 65 + R2 % 65) * 512 + klane;
        offA3 = ((i0 + R3 / 65) * 65 + R3 % 65) * 512 + klane;
    }
    const __hip_bfloat16* bB = wp + (size_t)(o0 + m0j) * 512 + klane;

    // ---- per-tap constants (tap t -> (rt,ct) row-major over (nrt,nct)) ----
    // tap0: (0,0); tap1: nct==2 ? (0,1) : (1,0); tap2: (1,0); tap3: (1,1)
    const int rt1 = (nct == 2) ? 0 : 1, ct1 = (nct == 2) ? 1 : 0;
    const int aoffL = lrow * 32 + quad * 8;
    // A LDS offset: ((drp+wm)*65 + dsp)*32 + aoffL ; af[fm] at +fm*512
    const int aoff0 = ((ph ? 1 : 0)   + wm) * 2080 + (pw ? 1 : 0)   * 32 + aoffL;
    const int aoff1 = ((ph ? 1 : rt1) + wm) * 2080 + (pw ? 1 : ct1) * 32 + aoffL;
    const int aoff2 = ((ph ? 1 : 1)   + wm) * 2080 + (pw ? 1 : 0)   * 32 + aoffL;
    const int aoff3 = ((ph ? 1 : 1)   + wm) * 2080 + (pw ? 1 : 1)   * 32 + aoffL;
    // B matrix index ab = a*3+b, scaled to elems (256*512)
    const int ab0 = ((ph ? 1 : 2) * 3 + (pw ? 1 : 2)) * 131072;
    const int ab1 = ((ph ? 1 : (rt1 ? 0 : 2)) * 3 + (pw ? 1 : (ct1 ? 0 : 2))) * 131072;
    const int ab2 = ((ph ? 1 : 0) * 3 + (pw ? 1 : 2)) * 131072;
    const int ab3 = ((ph ? 1 : 0) * 3 + (pw ? 1 : 0)) * 131072;

    const int boff = (wn * 64 + lrow) * 32 + quad * 8;

    auto compute_tap = [&](int aoffT, const __hip_bfloat16* lBt) {
        short8 af[4], bv[4];
#pragma unroll
        for (int fm = 0; fm < 4; fm++)
            af[fm] = *(const short8*)(lA + aoffT + fm * 512);
#pragma unroll
        for (int fn = 0; fn < 4; fn++)
            bv[fn] = *(const short8*)(lBt + boff + fn * 512);
#pragma unroll
        for (int fm = 0; fm < 4; fm++)
#pragma unroll
            for (int fn = 0; fn < 4; fn++)
                acc[fm][fn] = __builtin_amdgcn_mfma_f32_16x16x32_bf16(
                    af[fm], bv[fn], acc[fm][fn], 0, 0, 0);
    };

    for (int c0 = 0; c0 < 512; c0 += 32) {
        __syncthreads();                         // prior reads done, overwrite ok
        gl_lds16(bA + offA0 + c0, lA +        wave * 512);
        gl_lds16(bA + offA1 + c0, lA + 2048 + wave * 512);
        gl_lds16(bA + offA2 + c0, lA + 4096 + wave * 512);
        gl_lds16(bA + offA3 + c0, lA + 6144 + wave * 512);
        gl_lds16(bB + (ab0 + c0),         lB +        wave * 512);
        gl_lds16(bB + (ab0 + 32768 + c0), lB + 2048 + wave * 512);
        if (nt > 1) {
            gl_lds16(bB + (ab1 + c0),         lB + 4096 + wave * 512);
            gl_lds16(bB + (ab1 + 32768 + c0), lB + 6144 + wave * 512);
        }
        if (nt > 2) {
            gl_lds16(bB + (ab2 + c0),         lB + 8192  + wave * 512);
            gl_lds16(bB + (ab2 + 32768 + c0), lB + 10240 + wave * 512);
            gl_lds16(bB + (ab3 + c0),         lB + 12288 + wave * 512);
            gl_lds16(bB + (ab3 + 32768 + c0), lB + 14336 + wave * 512);
        }
        __syncthreads();                         // stage drained (vmcnt0 + bar)
        compute_tap(aoff0, lB);
        if (nt > 1) compute_tap(aoff1, lB + 4096);
        if (nt > 2) {
            compute_tap(aoff2, lB + 8192);
            compute_tap(aoff3, lB + 12288);
        }
    }

    // epilogue: D row=(quad*4+reg) -> j, col=lrow -> o ; 4 consecutive j per lane
#pragma unroll
    for (int fm = 0; fm < 4; fm++) {
        int j0 = fm * 16 + quad * 4;
#pragma unroll
        for (int fn = 0; fn < 4; fn++) {
            int o = o0 + wn * 64 + fn * 16 + lrow;
            union { ushort4 v; __hip_bfloat16 h[4]; } u;
#pragma unroll
            for (int r = 0; r < 4; r++) u.h[r] = __float2bfloat16(acc[fm][fn][r]);
            *(ushort4*)(yp + (((size_t)(p * 4096 + n * 256 + o)) << 12) +
                        ((i0 + wm) << 6) + j0) = u.v;
        }
    }
}

// ---------------------------------------------------------------- FIR -------
// grid (4096 no, 2 row-halves). LDS [q][33][64]: slot 0 = halo row (h*32-1),
// slots 1..32 = window rows [h*32, h*32+32). h=0 slot 0 unread (ih>=0 pred).
__device__ __forceinline__ float bf_lo(unsigned u) { return __uint_as_float(u << 16); }
__device__ __forceinline__ float bf_hi(unsigned u) { return __uint_as_float(u & 0xffff0000u); }

__global__ __launch_bounds__(256) void fir_kernel(
    const __hip_bfloat16* __restrict__ yp, float* __restrict__ out) {
    const int no  = blockIdx.x;          // n*256 + o
    const int h   = blockIdx.y;          // row half
    const int tid = (int)threadIdx.x;

    __shared__ __align__(16) unsigned short ylds[4][33][64];   // 16.9KB

    const unsigned short* ysrc = (const unsigned short*)yp;
    // window: 4 planes x 32 rows x 64 = 1024 short8 chunks, 4 per thread
#pragma unroll
    for (int k = 0; k < 4; k++) {
        int chunk = k * 256 + tid;           // 0..1023
        int q    = chunk >> 8;               // 0..3
        int idx  = chunk & 255;
        int r    = idx >> 3;                 // 0..31
        int col8 = idx & 7;
        *(short8*)(&ylds[q][r + 1][col8 * 8]) =
            *(const short8*)(ysrc + (((size_t)(q * 4096 + no)) << 12) +
                             (h * 32 + r) * 64 + col8 * 8);
    }
    if (h == 1 && tid < 32) {                // halo row 31 -> slot 0
        int q = tid >> 3, col8 = tid & 7;
        *(short8*)(&ylds[q][0][col8 * 8]) =
            *(const short8*)(ysrc + (((size_t)(q * 4096 + no)) << 12) +
                             31 * 64 + col8 * 8);
    }
    __syncthreads();

    const unsigned* yw = (const unsigned*)ylds;  // word view, row stride 32

    const int qp = tid & 31;     // quad-pair: covers out cols 4qp..4qp+3
    const int iw = tid >> 5;     // 0..7

    // weight of plane-parity q, offset k, for output sub-parity e
    const float rw[2][2][2] = {{{0.4f, 0.4f}, {1.2f, 0.f}},
                               {{0.f, 1.2f}, {0.4f, 0.4f}}};  // [e][q][k]

    for (int s = 0; s < 4; s++) {
        const int Il = s * 8 + iw;           // 0..31 local
        const int I  = h * 32 + Il;          // global (out rows 2I, 2I+1)

        // Y3[ph][pw][k][m]: cols {2qp-1,2qp,2qp+1} of plane, y row I-1+k
        // LDS slot = Il + k  (slot s' holds y row h*32 + s' - 1)
        float Y3[2][2][2][3];
#pragma unroll
        for (int q = 0; q < 4; q++) {
            int phh = q >> 1, pww = q & 1;
#pragma unroll
            for (int k = 0; k < 2; k++) {
                float c0 = 0.f, c1 = 0.f, c2 = 0.f;
                if (I - 1 + k >= 0) {
                    const unsigned* row = yw + (q * 33 + Il + k) * 32;
                    unsigned wb = row[qp];
                    c1 = bf_lo(wb);
                    c2 = bf_hi(wb);
                    if (qp > 0) c0 = bf_hi(row[qp - 1]);
                }
                Y3[phh][pww][k][0] = c0;
                Y3[phh][pww][k][1] = c1;
                Y3[phh][pww][k][2] = c2;
            }
        }

        float res[2][4];
#pragma unroll
        for (int t = 0; t < 2; t++) {        // quad t: J = 2qp+t, taps cols {t,t+1}
            float cs[2][2][2];               // [ph][k][ew]
#pragma unroll
            for (int phh = 0; phh < 2; phh++)
#pragma unroll
                for (int k = 0; k < 2; k++)
#pragma unroll
                    for (int ew = 0; ew < 2; ew++) {
                        float sv = 0.f;
#pragma unroll
                        for (int pww = 0; pww < 2; pww++)
#pragma unroll
                            for (int l = 0; l < 2; l++)
                                sv += rw[ew][pww][l] * Y3[phh][pww][k][t + l];
                        cs[phh][k][ew] = sv;
                    }
#pragma unroll
            for (int eh = 0; eh < 2; eh++)
#pragma unroll
                for (int ew = 0; ew < 2; ew++) {
                    float sv = 0.f;
#pragma unroll
                    for (int phh = 0; phh < 2; phh++)
#pragma unroll
                        for (int k = 0; k < 2; k++)
                            sv += rw[eh][phh][k] * cs[phh][k][ew];
                    res[eh][t * 2 + ew] = sv;
                }
        }

        size_t base = ((size_t)no << 14) + ((size_t)(2 * I) << 7) + 4 * qp;
        float4v v0 = {res[0][0], res[0][1], res[0][2], res[0][3]};
        float4v v1 = {res[1][0], res[1][1], res[1][2], res[1][3]};
        *(float4v*)(out + base)       = v0;
        *(float4v*)(out + base + 128) = v1;
    }
}

// ------------------------------------------------- fallback (ws too small) --
__global__ __launch_bounds__(256) void fused_direct_kernel(
    const float* __restrict__ x, const float* __restrict__ w,
    float* __restrict__ out) {
    int idx = blockIdx.x * 256 + (int)threadIdx.x;
    int w_ = idx & 127, h = (idx >> 7) & 127, no = idx >> 14;
    int o = no & 255, n = no >> 8;
    int I = h >> 1, J = w_ >> 1;
    const float fr0 = 0.4f, fr1 = 1.2f, fr2 = 0.4f;
    float gh[3][3]; int rh[3]; int nh;
    if ((h & 1) == 0) {
        nh = 3;
        rh[0] = I - 2; gh[0][0] = 0.f; gh[0][1] = 0.f; gh[0][2] = fr0;
        rh[1] = I - 1; gh[1][0] = fr0; gh[1][1] = fr1; gh[1][2] = fr2;
        rh[2] = I;     gh[2][0] = fr2; gh[2][1] = 0.f; gh[2][2] = 0.f;
    } else {
        nh = 2;
        rh[0] = I - 1; gh[0][0] = 0.f; gh[0][1] = fr0; gh[0][2] = fr1;
        rh[1] = I;     gh[1][0] = fr1; gh[1][1] = fr2; gh[1][2] = 0.f;
    }
    float gw[3][3]; int cw[3]; int nw;
    if ((w_ & 1) == 0) {
        nw = 3;
        cw[0] = J - 2; gw[0][0] = 0.f; gw[0][1] = 0.f; gw[0][2] = fr0;
        cw[1] = J - 1; gw[1][0] = fr0; gw[1][1] = fr1; gw[1][2] = fr2;
        cw[2] = J;     gw[2][0] = fr2; gw[2][1] = 0.f; gw[2][2] = 0.f;
    } else {
        nw = 2;
        cw[0] = J - 1; gw[0][0] = 0.f; gw[0][1] = fr0; gw[0][2] = fr1;
        cw[1] = J;     gw[1][0] = fr1; gw[1][1] = fr2; gw[1][2] = 0.f;
    }
    float acc = 0.f;
    for (int c = 0; c < 512; c++) {
        const float* xb = x + ((size_t)(n * 512 + c) << 12);
        const float* wb = w + (size_t)(c * 256 + o) * 9;
        float tmp[3][3];
#pragma unroll
        for (int dr = 0; dr < 3; dr++) tmp[dr][0] = tmp[dr][1] = tmp[dr][2] = 0.f;
        for (int dr = 0; dr < nh; dr++) {
            int r = rh[dr]; if (r < 0) continue;
            for (int ds = 0; ds < nw; ds++) {
                int s = cw[ds]; if (s < 0) continue;
                float xv = xb[(r << 6) + s];
                tmp[dr][0] += gw[ds][0] * xv;
                tmp[dr][1] += gw[ds][1] * xv;
                tmp[dr][2] += gw[ds][2] * xv;
            }
        }
#pragma unroll
        for (int a = 0; a < 3; a++) {
            float xg0 = 0.f, xg1 = 0.f, xg2 = 0.f;
            for (int dr = 0; dr < nh; dr++) {
                float g = gh[dr][a];
                xg0 += g * tmp[dr][0]; xg1 += g * tmp[dr][1]; xg2 += g * tmp[dr][2];
            }
            acc += xg0 * wb[a * 3] + xg1 * wb[a * 3 + 1] + xg2 * wb[a * 3 + 2];
        }
    }
    out[idx] = acc;
}

// ---------------------------------------------------------------- launch ----
extern "C" void kernel_launch(void* const* d_in, const int* in_sizes, int n_in,
                              void* d_out, int out_size, void* d_ws, size_t ws_size,
                              hipStream_t stream)
{
    (void)in_sizes; (void)n_in; (void)out_size;
    const float* x = (const float*)d_in[0];   // (16,512,64,64)
    const float* w = (const float*)d_in[1];   // (256,512,3,3)
    float* out = (float*)d_out;               // (16,256,128,128)

    const size_t need = (XP_ELEMS + WP_ELEMS + YP_ELEMS) * sizeof(__hip_bfloat16);
    if (ws_size >= need) {
        __hip_bfloat16* xp = (__hip_bfloat16*)d_ws;
        __hip_bfloat16* wp = xp + XP_ELEMS;
        __hip_bfloat16* yp = wp + WP_ELEMS;
        prep_kernel<<<dim3((int)(WP_ELEMS / 256)), dim3(256), 0, stream>>>(w, wp, xp);
        pack_x_kernel<<<dim3(64, 16, 2), dim3(256), 0, stream>>>(x, xp);
        mfma_conv_kernel<<<dim3(2, 512, 4), dim3(256), 0, stream>>>(xp, wp, yp);
        fir_kernel<<<dim3(4096, 2), dim3(256), 0, stream>>>(yp, out);
    } else {
        fused_direct_kernel<<<dim3((int)(YP_ELEMS / 256)), dim3(256), 0, stream>>>(x, w, out);
    }
}